// Round 2
// baseline (1315.900 us; speedup 1.0000x reference)
//
#include <hip/hip_runtime.h>

#define N_NODES 100000
#define N_EDGES 3200000
#define N_GRAPHS 2048
#define NB 1563            // ceil(100000/64) buckets of 64 dst nodes

// ---------- bucket build ----------

// per-block LDS histogram of bucket ids, merged with one atomic per nonzero bin
__global__ void k_bcount(const int* __restrict__ dst, int* __restrict__ bcnt) {
  __shared__ int hist[NB];
  int tid = threadIdx.x;
  for (int i = tid; i < NB; i += 256) hist[i] = 0;
  __syncthreads();
  for (int e = blockIdx.x * 256 + tid; e < N_EDGES; e += gridDim.x * 256)
    atomicAdd(&hist[dst[e] >> 6], 1);
  __syncthreads();
  for (int i = tid; i < NB; i += 256)
    if (hist[i]) atomicAdd(&bcnt[i], hist[i]);
}

// single-block exclusive scan over NB bucket counts
__global__ void k_bscan(const int* __restrict__ bcnt, int* __restrict__ boffs) {
  __shared__ int sh[256];
  __shared__ int carry;
  int tid = threadIdx.x;
  if (tid == 0) carry = 0;
  __syncthreads();
  for (int c = 0; c < NB; c += 256) {
    int i = c + tid;
    int v = (i < NB) ? bcnt[i] : 0;
    sh[tid] = v;
    __syncthreads();
    for (int off = 1; off < 256; off <<= 1) {
      int t = (tid >= off) ? sh[tid - off] : 0;
      __syncthreads();
      sh[tid] += t;
      __syncthreads();
    }
    if (i < NB) boffs[i] = carry + sh[tid] - v;
    __syncthreads();                 // everyone reads carry before update
    if (tid == 255) carry += sh[255];
    __syncthreads();
  }
  if (tid == 0) boffs[NB] = N_EDGES;
}

// append packed (src<<6)|local into bucket region — dense writes, L2 merges lines
__global__ void k_bfill(const int* __restrict__ src, const int* __restrict__ dst,
                        const int* __restrict__ boffs, int* __restrict__ bcur,
                        unsigned* __restrict__ stage) {
  int e = blockIdx.x * 256 + threadIdx.x;
  if (e < N_EDGES) {
    int d = dst[e];
    int b = d >> 6;
    int p = atomicAdd(&bcur[b], 1);
    stage[boffs[b] + p] = ((unsigned)src[e] << 6) | (unsigned)(d & 63);
  }
}

// per-node degree -> dinv, recovered bucket-locally (no global atomics)
__global__ void k_bdeg(const unsigned* __restrict__ stage, const int* __restrict__ boffs,
                       float* __restrict__ dinv) {
  __shared__ int cnt[64];
  int b = blockIdx.x, tid = threadIdx.x;
  if (tid < 64) cnt[tid] = 0;
  __syncthreads();
  int beg = boffs[b], end = boffs[b + 1];
  for (int k = beg + tid; k < end; k += 256) atomicAdd(&cnt[stage[k] & 63], 1);
  __syncthreads();
  if (tid < 64) {
    int node = b * 64 + tid;
    if (node < N_NODES) dinv[node] = rsqrtf((float)(cnt[tid] + 1));  // +1 self-loop
  }
}

__global__ void k_count_graph(const int* __restrict__ batch, int* __restrict__ gcnt) {
  int i = blockIdx.x * blockDim.x + threadIdx.x;
  if (i < N_NODES) atomicAdd(&gcnt[batch[i]], 1);
}

// ---------- layer 1: g1 = (x@W1)*dinv ----------

__global__ void k_t1(const float* __restrict__ x, const float* __restrict__ W1,
                     const float* __restrict__ dinv, float* __restrict__ g1) {
  __shared__ float w[150];
  int tid = threadIdx.x;
  if (tid < 150) w[tid] = W1[tid];
  __syncthreads();
  int gid = blockIdx.x * blockDim.x + tid;
  if (gid < N_NODES * 30) {
    int node = gid / 30, col = gid - node * 30;
    const float* xr = x + node * 5;
    float acc = 0.f;
#pragma unroll
    for (int k = 0; k < 5; k++) acc += xr[k] * w[k * 30 + col];
    g1[gid] = acc * dinv[node];
  }
}

// bucket-local aggregation: LDS acc[64][30], (edge,col)-parallel lanes
__global__ void k_agg1_b(const float* __restrict__ g1, const float* __restrict__ dinv,
                         const int* __restrict__ boffs, const unsigned* __restrict__ stage,
                         const float* __restrict__ b1, float* __restrict__ a1) {
  __shared__ float acc[64 * 30];
  int b = blockIdx.x, tid = threadIdx.x;
  for (int i = tid; i < 64 * 30; i += 256) acc[i] = 0.f;
  __syncthreads();
  int beg = boffs[b], end = boffs[b + 1];
  int lane = tid & 31, eoff = tid >> 5;            // 8 edges per pass
  for (int k = beg + eoff; k < end; k += 8) {
    unsigned v = stage[k];
    int s = v >> 6, local = v & 63;
    if (lane < 30) atomicAdd(&acc[local * 30 + lane], g1[s * 30 + lane]);
  }
  __syncthreads();
  for (int i = tid; i < 64 * 30; i += 256) {
    int local = i / 30, col = i - local * 30;
    int node = b * 64 + local;
    if (node < N_NODES) {
      float v = dinv[node] * (g1[node * 30 + col] + acc[i]) + b1[col];
      a1[node * 30 + col] = fmaxf(v, 0.f);
    }
  }
}

// ---------- layer 2: g2 = (a1@W2)*dinv ----------

__global__ void k_t2(const float* __restrict__ a1, const float* __restrict__ W2,
                     const float* __restrict__ dinv, float* __restrict__ g2) {
  __shared__ float w[240];
  int tid = threadIdx.x;
  if (tid < 240) w[tid] = W2[tid];
  __syncthreads();
  int gid = blockIdx.x * blockDim.x + tid;
  if (gid < N_NODES * 8) {
    int node = gid >> 3, col = gid & 7;
    const float* ar = a1 + node * 30;
    float acc = 0.f;
#pragma unroll
    for (int k = 0; k < 30; k++) acc += ar[k] * w[k * 8 + col];
    g2[gid] = acc * dinv[node];
  }
}

// bucket-local aggregation + graph-mean pooling accumulate
__global__ void k_agg2_b(const float* __restrict__ g2, const float* __restrict__ dinv,
                         const int* __restrict__ boffs, const unsigned* __restrict__ stage,
                         const float* __restrict__ b2, const int* __restrict__ batch,
                         float* __restrict__ gsum) {
  __shared__ float acc[64 * 8];
  int b = blockIdx.x, tid = threadIdx.x;
  for (int i = tid; i < 64 * 8; i += 256) acc[i] = 0.f;
  __syncthreads();
  int beg = boffs[b], end = boffs[b + 1];
  int lane = tid & 7, eoff = tid >> 3;             // 32 edges per pass
  for (int k = beg + eoff; k < end; k += 32) {
    unsigned v = stage[k];
    int s = v >> 6, local = v & 63;
    atomicAdd(&acc[local * 8 + lane], g2[s * 8 + lane]);
  }
  __syncthreads();
  for (int i = tid; i < 64 * 8; i += 256) {
    int local = i >> 3, col = i & 7;
    int node = b * 64 + local;
    if (node < N_NODES) {
      float v = dinv[node] * (g2[node * 8 + col] + acc[i]) + b2[col];
      atomicAdd(&gsum[batch[node] * 8 + col], v);
    }
  }
}

__global__ void k_final(const float* __restrict__ gsum, const int* __restrict__ gcnt,
                        float* __restrict__ out) {
  int i = blockIdx.x * blockDim.x + threadIdx.x;
  if (i < N_GRAPHS * 8) {
    float c = (float)gcnt[i >> 3];
    out[i] = gsum[i] / fmaxf(c, 1.f);
  }
}

extern "C" void kernel_launch(void* const* d_in, const int* in_sizes, int n_in,
                              void* d_out, int out_size, void* d_ws, size_t ws_size,
                              hipStream_t stream) {
  const float* x    = (const float*)d_in[0];
  const int* ei     = (const int*)d_in[1];
  const int* batch  = (const int*)d_in[2];
  const float* W1   = (const float*)d_in[3];
  const float* b1   = (const float*)d_in[4];
  const float* W2   = (const float*)d_in[5];
  const float* b2   = (const float*)d_in[6];
  const int* srcp = ei;
  const int* dstp = ei + N_EDGES;
  float* out = (float*)d_out;

  // workspace carve (~37.5 MB)
  char* base = (char*)d_ws;
  size_t o = 0;
  auto carve = [&](size_t bytes) -> char* {
    char* p = base + o;
    o += (bytes + 255) & ~(size_t)255;
    return p;
  };
  int* bcnt       = (int*)carve((size_t)NB * 4);
  int* bcur       = (int*)carve((size_t)NB * 4);
  int* boffs      = (int*)carve((size_t)(NB + 1) * 4);
  unsigned* stage = (unsigned*)carve((size_t)N_EDGES * 4);
  float* dinv     = (float*)carve((size_t)N_NODES * 4);
  float* g1       = (float*)carve((size_t)N_NODES * 30 * 4);
  float* a1       = (float*)carve((size_t)N_NODES * 30 * 4);
  float* gsum     = (float*)carve((size_t)N_GRAPHS * 8 * 4);
  int* gcnt       = (int*)carve((size_t)N_GRAPHS * 4);
  float* g2 = g1;  // g1 dead after k_agg1_b

  hipMemsetAsync(bcnt, 0, (size_t)NB * 4, stream);
  hipMemsetAsync(bcur, 0, (size_t)NB * 4, stream);
  hipMemsetAsync(gsum, 0, (size_t)N_GRAPHS * 8 * 4, stream);
  hipMemsetAsync(gcnt, 0, (size_t)N_GRAPHS * 4, stream);

  int nb_e = (N_EDGES + 255) / 256;
  int nb_n = (N_NODES + 255) / 256;

  k_bcount<<<512, 256, 0, stream>>>(dstp, bcnt);
  k_bscan<<<1, 256, 0, stream>>>(bcnt, boffs);
  k_bfill<<<nb_e, 256, 0, stream>>>(srcp, dstp, boffs, bcur, stage);
  k_bdeg<<<NB, 256, 0, stream>>>(stage, boffs, dinv);
  k_count_graph<<<nb_n, 256, 0, stream>>>(batch, gcnt);

  k_t1<<<(N_NODES * 30 + 255) / 256, 256, 0, stream>>>(x, W1, dinv, g1);
  k_agg1_b<<<NB, 256, 0, stream>>>(g1, dinv, boffs, stage, b1, a1);
  k_t2<<<(N_NODES * 8 + 255) / 256, 256, 0, stream>>>(a1, W2, dinv, g2);
  k_agg2_b<<<NB, 256, 0, stream>>>(g2, dinv, boffs, stage, b2, batch, gsum);
  k_final<<<(N_GRAPHS * 8 + 255) / 256, 256, 0, stream>>>(gsum, gcnt, out);
}